// Round 4
// baseline (237.305 us; speedup 1.0000x reference)
//
#include <hip/hip_runtime.h>

typedef __attribute__((ext_vector_type(8))) short short8;   // 8 bf16 (4 VGPRs) MFMA A/B frag
typedef __attribute__((ext_vector_type(4))) float f32x4;    // MFMA C/D frag

constexpr int GRID  = 8192;                      // 1 row-tile (64 rows) per block
constexpr float L2E2 = 2.8853900817779268f;      // 2*log2(e)

union V16 { uint4 u; short8 s; };

// round-half-up bf16 pair pack: (bits+0x8000)>>16, two elems -> one u32 via v_perm.
__device__ __forceinline__ unsigned pk(float lo, float hi) {
  const unsigned a = __float_as_uint(lo) + 0x8000u;
  const unsigned b = __float_as_uint(hi) + 0x8000u;
  return __builtin_amdgcn_perm(b, a, 0x07060302u);  // dst = [a.hi16, b.hi16]
}

__device__ __forceinline__ V16 pk8(f32x4 a, f32x4 b) {
  V16 v;
  v.u.x = pk(a[0], a[1]); v.u.y = pk(a[2], a[3]);
  v.u.z = pk(b[0], b[1]); v.u.w = pk(b[2], b[3]);
  return v;
}

// One 64-row tile per block (GRID=8192): issue x loads -> W1/const setup under
// the HBM-latency shadow -> pack x to xb -> barrier -> compute -> direct store.
// No multi-tile pipeline: drops pf double-buffer (-16 persistent VGPR) and the
// cross-iteration in-order-DS coupling; 32 small blocks/CU backfill evenly.
//
// Math: out[b,k] = sigmoid(2S), exp2-arg accumulated directly:
//   arg = -L2E2*(b2+sum w2) + sum_h (2*L2E2*w2_h)/(exp2(L2E2*a_h)+1),  a=W1x+b1
//   out = rcp(exp2(arg)+1)
// Hidden-unit reciprocals are 4-way combined (exact):
//   sum_r w_r/f_r = N/D;  f=e+1, p01=f0*f1, p23=f2*f3, D=p01*p23,
//   n01=fma(w0,f1,w1*f0), n23=fma(w2,f3,w3*f2), N=fma(n01,p23,n23*p01)
// -> per quad: 4 exp2 + 1 rcp (was 4+4): hidden trans 128 -> 80 per wave-tile.
// KSbn is pre-quartered and used as the P-seed: the 4 q-group shfl-reduce then
// sums 4*(KSbn/4) + partials = full bias term, no post-reduce fma needed.
//
// launch_bounds stays (256,4): (256,8) clamps the allocator to 32 arch-VGPRs
// (unified-file split accounting) and spills everything (round-1: 833MB
// scratch fetch, 294us/dispatch).
__global__ __launch_bounds__(256, 4) void fused_mlp8(
    const float* __restrict__ x, const float* __restrict__ W1,
    const float* __restrict__ b1, const float* __restrict__ W2,
    const float* __restrict__ b2, float* __restrict__ out) {

  // x: 64 rows x 8 chunks(16B); chunk c of row r at r*8 + (c ^ (r&7))
  __shared__ V16 xb[512];   // 8 KiB

  const int tid  = threadIdx.x;
  const int wave = tid >> 6;
  const int lane = tid & 63;
  const int m16  = lane & 15;
  const int q    = lane >> 4;

  // ---- issue the x-tile loads FIRST; W1/const setup hides their latency
  const int srow = tid >> 2;           // staging row 0..63
  const int seg  = tid & 3;            // 16-float segment
  const int sw   = srow & 7;
  const float* gx = x + blockIdx.x * 4096 + srow * 64 + seg * 16;
  const f32x4 pf0 = *(const f32x4*)gx;
  const f32x4 pf1 = *(const f32x4*)(gx + 4);
  const f32x4 pf2 = *(const f32x4*)(gx + 8);
  const f32x4 pf3 = *(const f32x4*)(gx + 12);

  // ---- W1 A-fragments (scaled by L2E2): lane holds rows n=(4w+mt)*16+m16
  short8 w1f[4][2];
#pragma unroll
  for (int mt = 0; mt < 4; ++mt) {
    const int n = (wave * 4 + mt) * 16 + m16;
#pragma unroll
    for (int ks = 0; ks < 2; ++ks) {
      const float* p = W1 + n * 64 + ks * 32 + q * 8;
      const f32x4 u0 = *(const f32x4*)p, u1 = *(const f32x4*)(p + 4);
      f32x4 s0, s1;
#pragma unroll
      for (int r = 0; r < 4; ++r) { s0[r] = L2E2 * u0[r]; s1[r] = L2E2 * u1[r]; }
      w1f[mt][ks] = pk8(s0, s1).s;
    }
  }

  // ---- folded per-lane constants for C-layout rows n0 = (4w+mt)*16 + 4q
  f32x4 kb1[4], w2q[4];
  float sw2[2] = {0.f, 0.f};
#pragma unroll
  for (int mt = 0; mt < 4; ++mt) {
    const int n0 = (wave * 4 + mt) * 16 + q * 4;
    const f32x4 b1x = *(const f32x4*)(b1 + n0);
    const f32x4 w2x = *(const f32x4*)(W2 + n0);
#pragma unroll
    for (int r = 0; r < 4; ++r) {
      kb1[mt][r] = L2E2 * b1x[r];
      w2q[mt][r] = (2.0f * L2E2) * w2x[r];   // +2*L2E2*w2: exp2-arg contribution
      sw2[mt >> 1] += w2x[r];
    }
  }
  float KSbn[2];   // pre-quartered bias term, used as P-seed (see header)
#pragma unroll
  for (int j = 0; j < 2; ++j) {
    float s = sw2[j];
    s += __shfl_xor(s, 16);
    s += __shfl_xor(s, 32);
    KSbn[j] = -0.25f * L2E2 * (s + b2[wave * 2 + j]);
  }

  // ---- pack x regs -> xb, one barrier
  xb[srow * 8 + ((seg * 2)     ^ sw)] = pk8(pf0, pf1);
  xb[srow * 8 + ((seg * 2 + 1) ^ sw)] = pk8(pf2, pf3);
  __syncthreads();

  const int obase = blockIdx.x * 512 + wave * 2;   // out floats, col = wave*2

  // ---- compute: 4 sub-tiles of 16 batch rows; q==0 lanes store direct
#pragma unroll
  for (int tt = 0; tt < 4; ++tt) {
    const int r   = tt * 16 + m16;
    const int rsw = r & 7;
    const short8 xf0 = xb[r * 8 + (q       ^ rsw)].s;
    const short8 xf1 = xb[r * 8 + ((q + 4) ^ rsw)].s;

    f32x4 acc[4];
#pragma unroll
    for (int mt = 0; mt < 4; ++mt) {
      f32x4 z = kb1[mt];   // bias pre-folded as MFMA C-init
      z = __builtin_amdgcn_mfma_f32_16x16x32_bf16(w1f[mt][0], xf0, z, 0, 0, 0);
      z = __builtin_amdgcn_mfma_f32_16x16x32_bf16(w1f[mt][1], xf1, z, 0, 0, 0);
      acc[mt] = z;
    }

    float o0 = 0.f, o1 = 0.f;
#pragma unroll
    for (int j = 0; j < 2; ++j) {
      float P = KSbn[j];   // quarter-bias seed; 4-group reduce restores full
#pragma unroll
      for (int t = 0; t < 2; ++t) {
        const int mt = j * 2 + t;
        // 4-way combined sum of w/(e+1) over rr=0..3: one rcp per quad
        const float e0 = __builtin_amdgcn_exp2f(acc[mt][0]);
        const float e1 = __builtin_amdgcn_exp2f(acc[mt][1]);
        const float e2 = __builtin_amdgcn_exp2f(acc[mt][2]);
        const float e3 = __builtin_amdgcn_exp2f(acc[mt][3]);
        const float f0 = e0 + 1.0f, f1 = e1 + 1.0f;
        const float f2 = e2 + 1.0f, f3 = e3 + 1.0f;
        const float p01 = f0 * f1, p23 = f2 * f3;
        const float n01 = __builtin_fmaf(w2q[mt][0], f1, w2q[mt][1] * f0);
        const float n23 = __builtin_fmaf(w2q[mt][2], f3, w2q[mt][3] * f2);
        const float N   = __builtin_fmaf(n01, p23, n23 * p01);
        P = __builtin_fmaf(N, __builtin_amdgcn_rcpf(p01 * p23), P);
      }
      P += __shfl_xor(P, 16);
      P += __shfl_xor(P, 32);
      const float o = __builtin_amdgcn_rcpf(
          __builtin_amdgcn_exp2f(P) + 1.0f);
      if (j == 0) o0 = o; else o1 = o;
    }

    if (q == 0) {  // direct store: 16 lanes x 8B at 32B stride; L2 merges
      float2 st; st.x = o0; st.y = o1;
      *(float2*)(out + obase + r * 8) = st;
    }
  }
}

extern "C" void kernel_launch(void* const* d_in, const int* in_sizes, int n_in,
                              void* d_out, int out_size, void* d_ws, size_t ws_size,
                              hipStream_t stream) {
  const float* x  = (const float*)d_in[0];
  const float* W1 = (const float*)d_in[1];
  const float* b1 = (const float*)d_in[2];
  const float* W2 = (const float*)d_in[3];
  const float* b2 = (const float*)d_in[4];
  float* out = (float*)d_out;
  fused_mlp8<<<GRID, 256, 0, stream>>>(x, W1, b1, W2, b2, out);
}

// Round 5
// 209.392 us; speedup vs baseline: 1.1333x; 1.1333x over previous
//
#include <hip/hip_runtime.h>

typedef __attribute__((ext_vector_type(8))) short short8;   // 8 bf16 (4 VGPRs) MFMA A/B frag
typedef __attribute__((ext_vector_type(4))) float f32x4;    // MFMA C/D frag

constexpr int B_ROWS   = 524288;
constexpr int ROWTILES = B_ROWS / 64;   // 8192 tiles of 64 rows
constexpr int GRID     = 2048;
constexpr int ITERS    = ROWTILES / GRID;   // 4 tiles per block
constexpr float L2E2   = 2.8853900817779268f;  // 2*log2(e)

union V16 { uint4 u; short8 s; };

// round-half-up bf16 pair pack: (bits+0x8000)>>16, two elems -> one u32 via v_perm.
__device__ __forceinline__ unsigned pk(float lo, float hi) {
  const unsigned a = __float_as_uint(lo) + 0x8000u;
  const unsigned b = __float_as_uint(hi) + 0x8000u;
  return __builtin_amdgcn_perm(b, a, 0x07060302u);  // dst = [a.hi16, b.hi16]
}

__device__ __forceinline__ V16 pk8(f32x4 a, f32x4 b) {
  V16 v;
  v.u.x = pk(a[0], a[1]); v.u.y = pk(a[2], a[3]);
  v.u.z = pk(b[0], b[1]); v.u.w = pk(b[2], b[3]);
  return v;
}

// 512-thread blocks, 8 waves, ONE classifier per wave (was 2 per wave in 4-wave
// blocks). Rationale: every prior round showed VGPR_Count=64 under
// launch_bounds(..,4) with occupancy pinned at ~40% -- the unified RF budget
// (128/wave, split evenly arch/acc per round-1's 32-at-budget-64 datapoint)
// caps residency at 4 waves/SIMD = 16 waves/CU. Halving per-wave state
// (w1f 32->16, kb1/w2q 16->8 each, pf 16->8, j-loop gone) targets <=64 total
// regs/wave -> 8 waves/SIMD -> 2x occupancy ceiling.
//
// Pipeline (round-0 structure, best measured): iter i: compute tile i from
// xb[p]; pack regs(tile i+1) -> xb[p^1]; ONE barrier; reload pf <- tile i+2.
// Math (round-4, exact algebra): out = sigmoid(2S) = rcp(exp2(P)+1), with the
// exp2-arg accumulated directly; per hidden-quad one rcp via 4-way fraction
// combining; L2E2*b1 folded into MFMA C-init; quarter-bias seeds P so the
// 4-group shfl reduce restores the full bias term.
// Store: lane keeps o of sub-tile tt==q; after the tt loop all 64 lanes store
// one float (row = lane) -- no q==0 divergence, 1 store/wave/tile.
//
// launch_bounds stays (512,4): round 1 proved min-waves=8 clamps arch VGPRs
// to 32 and spills everything (833MB scratch traffic).
__global__ __launch_bounds__(512, 4) void fused_mlp8(
    const float* __restrict__ x, const float* __restrict__ W1,
    const float* __restrict__ b1, const float* __restrict__ W2,
    const float* __restrict__ b2, float* __restrict__ out) {

  // x: 2 buffers x 64 rows x 8 chunks(16B); chunk c of row r at r*8 + (c ^ (r&7))
  __shared__ V16 xb[2][512];   // 16 KiB

  const int tid  = threadIdx.x;
  const int wave = tid >> 6;        // classifier k = wave (K=8)
  const int lane = tid & 63;
  const int m16  = lane & 15;
  const int q    = lane >> 4;

  // ---- staging geometry: 512 threads cover 64 rows x 64 f32; 32B per thread
  const int srow = tid >> 3;        // row 0..63
  const int seg  = tid & 7;         // 8-float chunk 0..7
  const int sw   = srow & 7;
  const float* gbase = x + (long)srow * 64 + seg * 8;

  // ---- issue tile-0 loads FIRST; W1/const setup hides their latency
  f32x4 pf0 = *(const f32x4*)(gbase + (long)blockIdx.x * 4096);
  f32x4 pf1 = *(const f32x4*)(gbase + (long)blockIdx.x * 4096 + 4);

  // ---- W1 A-fragments (scaled by L2E2): this wave's classifier only.
  // lane holds hidden rows n = wave*32 + mt*16 + m16, elems ks*32 + q*8 ..+7
  short8 w1f[2][2];
#pragma unroll
  for (int mt = 0; mt < 2; ++mt) {
    const int n = wave * 32 + mt * 16 + m16;
#pragma unroll
    for (int ks = 0; ks < 2; ++ks) {
      const float* p = W1 + n * 64 + ks * 32 + q * 8;
      const f32x4 u0 = *(const f32x4*)p, u1 = *(const f32x4*)(p + 4);
      f32x4 s0, s1;
#pragma unroll
      for (int r = 0; r < 4; ++r) { s0[r] = L2E2 * u0[r]; s1[r] = L2E2 * u1[r]; }
      w1f[mt][ks] = pk8(s0, s1).s;
    }
  }

  // ---- folded per-lane constants, hidden units n0 = wave*32 + mt*16 + q*4
  f32x4 kb1[2], w2q[2];
  float s = 0.f;
#pragma unroll
  for (int mt = 0; mt < 2; ++mt) {
    const int n0 = wave * 32 + mt * 16 + q * 4;
    const f32x4 b1x = *(const f32x4*)(b1 + n0);
    const f32x4 w2x = *(const f32x4*)(W2 + n0);
#pragma unroll
    for (int r = 0; r < 4; ++r) {
      kb1[mt][r] = L2E2 * b1x[r];
      w2q[mt][r] = (2.0f * L2E2) * w2x[r];
      s += w2x[r];
    }
  }
  s += __shfl_xor(s, 16);
  s += __shfl_xor(s, 32);
  const float KSbn = -0.25f * L2E2 * (s + b2[wave]);  // quarter-bias P seed

  // ---- prologue: pack tile0 -> xb[0]; tile1 -> pf regs
  xb[0][srow * 8 + (seg ^ sw)] = pk8(pf0, pf1);
  pf0 = *(const f32x4*)(gbase + ((long)blockIdx.x + GRID) * 4096);
  pf1 = *(const f32x4*)(gbase + ((long)blockIdx.x + GRID) * 4096 + 4);
  __syncthreads();

#pragma unroll
  for (int i = 0; i < ITERS; ++i) {
    const int p = i & 1;
    const long tile = (long)blockIdx.x + (long)i * GRID;

    // ---- compute tile i from xb[p]; lane keeps o of sub-tile tt==q
    float osel = 0.f;
#pragma unroll
    for (int tt = 0; tt < 4; ++tt) {
      const int r   = tt * 16 + m16;
      const int rsw = r & 7;
      const short8 xf0 = xb[p][r * 8 + (q       ^ rsw)].s;
      const short8 xf1 = xb[p][r * 8 + ((q + 4) ^ rsw)].s;

      f32x4 acc[2];
#pragma unroll
      for (int mt = 0; mt < 2; ++mt) {
        f32x4 z = kb1[mt];   // bias pre-folded as MFMA C-init
        z = __builtin_amdgcn_mfma_f32_16x16x32_bf16(w1f[mt][0], xf0, z, 0, 0, 0);
        z = __builtin_amdgcn_mfma_f32_16x16x32_bf16(w1f[mt][1], xf1, z, 0, 0, 0);
        acc[mt] = z;
      }

      float P = KSbn;
#pragma unroll
      for (int mt = 0; mt < 2; ++mt) {
        // 4-way combined sum of w/(e+1): one rcp per hidden quad (exact)
        const float e0 = __builtin_amdgcn_exp2f(acc[mt][0]);
        const float e1 = __builtin_amdgcn_exp2f(acc[mt][1]);
        const float e2 = __builtin_amdgcn_exp2f(acc[mt][2]);
        const float e3 = __builtin_amdgcn_exp2f(acc[mt][3]);
        const float f0 = e0 + 1.0f, f1 = e1 + 1.0f;
        const float f2 = e2 + 1.0f, f3 = e3 + 1.0f;
        const float p01 = f0 * f1, p23 = f2 * f3;
        const float n01 = __builtin_fmaf(w2q[mt][0], f1, w2q[mt][1] * f0);
        const float n23 = __builtin_fmaf(w2q[mt][2], f3, w2q[mt][3] * f2);
        const float N   = __builtin_fmaf(n01, p23, n23 * p01);
        P = __builtin_fmaf(N, __builtin_amdgcn_rcpf(p01 * p23), P);
      }
      P += __shfl_xor(P, 16);
      P += __shfl_xor(P, 32);
      const float o = __builtin_amdgcn_rcpf(__builtin_amdgcn_exp2f(P) + 1.0f);
      osel = (tt == q) ? o : osel;   // branch-free select, stored after loop
    }

    // ---- all 64 lanes store one float: row = lane, col = classifier = wave
    out[(tile * 64 + lane) * 8 + wave] = osel;

    // ---- pack tile i+1 regs -> xb[p^1] (pre-barrier)
    if (i + 1 < ITERS) {
      xb[p ^ 1][srow * 8 + (seg ^ sw)] = pk8(pf0, pf1);
    }

    __syncthreads();   // the ONLY barrier per iteration

    // ---- issue tile i+2 loads; consumed at iteration i+1's pack
    if (i + 2 < ITERS) {
      const float* gp = gbase + (tile + 2 * GRID) * 4096;
      pf0 = *(const f32x4*)gp;
      pf1 = *(const f32x4*)(gp + 4);
    }
  }
}

extern "C" void kernel_launch(void* const* d_in, const int* in_sizes, int n_in,
                              void* d_out, int out_size, void* d_ws, size_t ws_size,
                              hipStream_t stream) {
  const float* x  = (const float*)d_in[0];
  const float* W1 = (const float*)d_in[1];
  const float* b1 = (const float*)d_in[2];
  const float* W2 = (const float*)d_in[3];
  const float* b2 = (const float*)d_in[4];
  float* out = (float*)d_out;
  fused_mlp8<<<GRID, 512, 0, stream>>>(x, W1, b1, W2, b2, out);
}